// Round 8
// baseline (244.111 us; speedup 1.0000x reference)
//
#include <hip/hip_runtime.h>
#include <hip/hip_bf16.h>

#define DD 128    // feature dim
#define HH 16     // hidden dim
#define BW 128    // bucket width (nodes per bucket) = 1<<7
#define NBMAX 1024
#define SCAP 4096      // LDS slice cap in sortagg (avg slice 2048, max ~2300)

// ---------------------------------------------------------------------------
// K_front: block-role fusion.
//   blocks [0, xblocks)              : y1 = x@w1_l, z1 = x@w1_r
//   blocks [xblocks, xblocks+cblocks): bucket histogram (4096 edges/block);
//                                      last-finishing block (ticket) performs
//                                      the exclusive bucket scan -> bstart,
//                                      gcursor, nodestart[N]
//   block  xblocks+cblocks           : classifier-collapse prep (wsu)
//     wsu[0..15]  = w2_l[j,:].wc[:128]    wsu[16..31] = w2_l[j,:].wc[128:]
//     wsu[32..47] = w2_r[j,:].wc[:128]    wsu[48..63] = w2_r[j,:].wc[128:]
//     wsu[64] = b2.wc[:128] + bc ;  wsu[65] = b2.wc[128:]
// ---------------------------------------------------------------------------
struct SmemXF { float wl[DD * HH]; float wr[DD * HH]; float xt[64 * 132]; };
struct SmemCT { int hist[NBMAX]; int wsum[4]; int tk; };
union SmemA { SmemXF xf; SmemCT ct; };

__global__ __launch_bounds__(256) void k_front(
    const int* __restrict__ dst, int* __restrict__ bcnt,
    int E4, int NB, int cblocks, int xblocks,
    const float* __restrict__ w2l, const float* __restrict__ w2r,
    const float* __restrict__ b2v, const float* __restrict__ wc,
    const float* __restrict__ bc, float* __restrict__ wsu,
    const float* __restrict__ x, const float* __restrict__ w1l,
    const float* __restrict__ w1r, float* __restrict__ y1,
    float* __restrict__ z1, int N,
    int* __restrict__ bstart, int* __restrict__ gcursor,
    int* __restrict__ nodestart, int* __restrict__ ticket2, int E) {
    __shared__ SmemA sm;
    const int tid = threadIdx.x;
    const int bi  = blockIdx.x;

    if (bi < xblocks) {                        // ---- xform role ----
        float* wl = sm.xf.wl;
        float* wr = sm.xf.wr;
        float* xt = sm.xf.xt;
        const int row0 = bi * 64;
        {
            const float4* a = (const float4*)w1l;
            const float4* b = (const float4*)w1r;
            ((float4*)wl)[tid]       = a[tid];
            ((float4*)wl)[tid + 256] = a[tid + 256];
            ((float4*)wr)[tid]       = b[tid];
            ((float4*)wr)[tid + 256] = b[tid + 256];
        }
#pragma unroll
        for (int k = 0; k < 8; ++k) {          // 64 rows x 32 f4
            int idx = tid + k * 256;
            int r = idx >> 5, c = idx & 31;
            if (row0 + r < N)
                ((float4*)xt)[r * 33 + c] =
                    ((const float4*)(x + (size_t)(row0 + r) * DD))[c];
        }
        __syncthreads();
        const int r = tid >> 2, seg = tid & 3;
        const int row = row0 + r;
        if (row >= N) return;
        float4 accy = {0.f, 0.f, 0.f, 0.f};
        float4 accz = {0.f, 0.f, 0.f, 0.f};
        const float* xrow = &xt[r * 132];
#pragma unroll 8
        for (int d = 0; d < DD; ++d) {
            float xv = xrow[d];
            float4 wl4 = *(const float4*)&wl[d * HH + seg * 4];
            float4 wr4 = *(const float4*)&wr[d * HH + seg * 4];
            accy.x += xv * wl4.x; accy.y += xv * wl4.y;
            accy.z += xv * wl4.z; accy.w += xv * wl4.w;
            accz.x += xv * wr4.x; accz.y += xv * wr4.y;
            accz.z += xv * wr4.z; accz.w += xv * wr4.w;
        }
        ((float4*)y1)[(size_t)row * 4 + seg] = accy;
        ((float4*)z1)[(size_t)row * 4 + seg] = accz;
        return;
    }

    if (bi == xblocks + cblocks) {             // ---- prep role ----
        if (tid < 64) {
            int k = tid >> 4, j = tid & 15;
            const float* W = (k < 2) ? w2l : w2r;
            int off = (k & 1) * DD;
            float s = 0.f;
            for (int d = 0; d < DD; ++d) s += W[j * DD + d] * wc[off + d];
            wsu[k * 16 + j] = s;
        } else if (tid == 64) {
            float s = bc[0];
            for (int d = 0; d < DD; ++d) s += b2v[d] * wc[d];
            wsu[64] = s;
        } else if (tid == 65) {
            float s = 0.f;
            for (int d = 0; d < DD; ++d) s += b2v[d] * wc[DD + d];
            wsu[65] = s;
        }
        return;
    }

    // ---- count role (4096 edges per block) ----
    const int cb = bi - xblocks;
    for (int i = tid; i < NB; i += 256) sm.ct.hist[i] = 0;
    __syncthreads();
    int base = cb * 1024;
#pragma unroll
    for (int k = 0; k < 4; ++k) {
        int i4 = base + k * 256 + tid;
        if (i4 < E4) {
            int4 d = ((const int4*)dst)[i4];
            atomicAdd(&sm.ct.hist[d.x >> 7], 1);
            atomicAdd(&sm.ct.hist[d.y >> 7], 1);
            atomicAdd(&sm.ct.hist[d.z >> 7], 1);
            atomicAdd(&sm.ct.hist[d.w >> 7], 1);
        }
    }
    __syncthreads();
    for (int i = tid; i < NB; i += 256) {
        int hv = sm.ct.hist[i];
        if (hv) atomicAdd(&bcnt[i], hv);
    }
    __threadfence();
    if (tid == 0) sm.ct.tk = atomicAdd(ticket2, 1);
    __syncthreads();
    if (sm.ct.tk != cblocks - 1) return;

    // ---- winner block: exclusive scan of bcnt[NB] (NB <= 1024) ----
    __threadfence();
    int idx0 = tid * 4;
    int v0 = (idx0 + 0 < NB) ? atomicAdd(&bcnt[idx0 + 0], 0) : 0;
    int v1 = (idx0 + 1 < NB) ? atomicAdd(&bcnt[idx0 + 1], 0) : 0;
    int v2 = (idx0 + 2 < NB) ? atomicAdd(&bcnt[idx0 + 2], 0) : 0;
    int v3 = (idx0 + 3 < NB) ? atomicAdd(&bcnt[idx0 + 3], 0) : 0;
    int tsum = v0 + v1 + v2 + v3;
    int lane = tid & 63, w = tid >> 6;
    int s = tsum;
#pragma unroll
    for (int off = 1; off < 64; off <<= 1) {
        int u = __shfl_up(s, off, 64);
        if (lane >= off) s += u;
    }
    if (lane == 63) sm.ct.wsum[w] = s;
    __syncthreads();
    int wbase = 0;
    for (int k = 0; k < w; ++k) wbase += sm.ct.wsum[k];
    int e0 = wbase + s - tsum;
    int e1 = e0 + v0, e2 = e1 + v1, e3 = e2 + v2;
    if (idx0 + 0 < NB) { bstart[idx0 + 0] = e0; gcursor[idx0 + 0] = e0; }
    if (idx0 + 1 < NB) { bstart[idx0 + 1] = e1; gcursor[idx0 + 1] = e1; }
    if (idx0 + 2 < NB) { bstart[idx0 + 2] = e2; gcursor[idx0 + 2] = e2; }
    if (idx0 + 3 < NB) { bstart[idx0 + 3] = e3; gcursor[idx0 + 3] = e3; }
    if (tid == 0) {
        bstart[NB] = sm.ct.wsum[0] + sm.ct.wsum[1] + sm.ct.wsum[2] + sm.ct.wsum[3];
        nodestart[N] = E;
    }
}

// ---------------------------------------------------------------------------
// K_bscatter: bucketed scatter (4096 edges/block). LDS hist -> bulk range
// reservation -> packed entries (local<<20 | src) into per-bucket ranges.
// ---------------------------------------------------------------------------
__global__ __launch_bounds__(256) void k_bscatter(const int* __restrict__ src,
                                                  const int* __restrict__ dst,
                                                  int* __restrict__ gcursor,
                                                  int* __restrict__ packed,
                                                  int E4, int NB) {
    __shared__ int hist[NBMAX];
    __shared__ int cur[NBMAX];
    for (int i = threadIdx.x; i < NB; i += 256) hist[i] = 0;
    __syncthreads();
    int base = blockIdx.x * 1024;
    int4 dreg[4];
#pragma unroll
    for (int k = 0; k < 4; ++k) {
        int i4 = base + k * 256 + threadIdx.x;
        if (i4 < E4) {
            int4 d = ((const int4*)dst)[i4];
            dreg[k] = d;
            atomicAdd(&hist[d.x >> 7], 1);
            atomicAdd(&hist[d.y >> 7], 1);
            atomicAdd(&hist[d.z >> 7], 1);
            atomicAdd(&hist[d.w >> 7], 1);
        }
    }
    __syncthreads();
    for (int i = threadIdx.x; i < NB; i += 256) {
        int hv = hist[i];
        cur[i] = hv ? atomicAdd(&gcursor[i], hv) : 0;
    }
    __syncthreads();
#pragma unroll
    for (int k = 0; k < 4; ++k) {
        int i4 = base + k * 256 + threadIdx.x;
        if (i4 < E4) {
            int4 sv = ((const int4*)src)[i4];
            int4 d = dreg[k];
            int p;
            p = atomicAdd(&cur[d.x >> 7], 1); packed[p] = ((d.x & 127) << 20) | sv.x;
            p = atomicAdd(&cur[d.y >> 7], 1); packed[p] = ((d.y & 127) << 20) | sv.y;
            p = atomicAdd(&cur[d.z >> 7], 1); packed[p] = ((d.z & 127) << 20) | sv.z;
            p = atomicAdd(&cur[d.w >> 7], 1); packed[p] = ((d.w & 127) << 20) | sv.w;
        }
    }
}

// ---------------------------------------------------------------------------
// K_sortagg: one block per bucket.
//   Phase A: counting-sort the bucket slice in LDS (stage buf -> sorted sbuf),
//            write nodestart + coalesced csr.
//   Phase B: layer-1 mean aggregation for the bucket's 128 nodes reading the
//            sorted slice from LDS:  h = relu(mean(y1[nbrs]) + b1 + z1)
// Global-memory fallback for oversized buckets (cnt > SCAP).
// ---------------------------------------------------------------------------
__global__ __launch_bounds__(256) void k_sortagg(const int* __restrict__ packed,
                                                 const int* __restrict__ bstart,
                                                 int* __restrict__ nodestart,
                                                 int* __restrict__ csr,
                                                 const float* __restrict__ y1,
                                                 const float* __restrict__ z1,
                                                 const float* __restrict__ b1,
                                                 float* __restrict__ h, int N) {
    __shared__ int buf[SCAP];
    __shared__ int sbuf[SCAP];
    __shared__ int hist[BW];
    __shared__ int exs[BW];
    __shared__ int curs[BW];
    __shared__ int wtot;
    const int tid = threadIdx.x;
    const int b = blockIdx.x;
    const int st = bstart[b], en = bstart[b + 1], cnt = en - st;
    const bool inlds = (cnt <= SCAP);

    if (tid < BW) hist[tid] = 0;
    __syncthreads();
    if (inlds) {
        for (int i = tid; i < cnt; i += 256) {
            int e = packed[st + i];
            buf[i] = e;
            atomicAdd(&hist[e >> 20], 1);
        }
    } else {
        for (int i = tid; i < cnt; i += 256)
            atomicAdd(&hist[packed[st + i] >> 20], 1);
    }
    __syncthreads();

    int v = 0, s = 0;
    if (tid < BW) {                            // 2-wave scan of 128 counts
        int lane = tid & 63;
        v = hist[tid];
        s = v;
#pragma unroll
        for (int off = 1; off < 64; off <<= 1) {
            int u = __shfl_up(s, off, 64);
            if (lane >= off) s += u;
        }
        if (tid == 63) wtot = s;
    }
    __syncthreads();
    if (tid < BW) {
        int ex = s - v + ((tid >= 64) ? wtot : 0);
        exs[tid] = ex;
        curs[tid] = ex;
        int node = (b << 7) + tid;
        if (node < N) nodestart[node] = st + ex;
    }
    __syncthreads();

    if (inlds) {
        for (int i = tid; i < cnt; i += 256) {
            int e = buf[i];
            int p = atomicAdd(&curs[e >> 20], 1);
            sbuf[p] = e & 0xFFFFF;
        }
        __syncthreads();
        for (int i = tid; i < cnt; i += 256) csr[st + i] = sbuf[i];  // coalesced
    } else {
        for (int i = tid; i < cnt; i += 256) {
            int e = packed[st + i];
            int p = atomicAdd(&curs[e >> 20], 1);
            csr[st + p] = e & 0xFFFFF;
        }
        __threadfence_block();
        __syncthreads();
    }

    // ---- Phase B: aggregate 128 nodes (4 lanes/node, 2 halves) ----
    const float4* f4 = (const float4*)y1;
#pragma unroll
    for (int half = 0; half < 2; ++half) {
        int l = (tid >> 2) + half * 64;
        int seg = tid & 3;
        int node = (b << 7) + l;
        if (node < N) {
            int s0 = exs[l], c = hist[l];
            float ax = 0.f, ay = 0.f, az = 0.f, aw = 0.f;
            int k = 0;
            if (inlds) {
                for (; k + 4 <= c; k += 4) {
                    int i0 = sbuf[s0 + k],     i1 = sbuf[s0 + k + 1];
                    int i2 = sbuf[s0 + k + 2], i3 = sbuf[s0 + k + 3];
                    float4 a = f4[(size_t)(i0 * 4 + seg)];
                    float4 bv = f4[(size_t)(i1 * 4 + seg)];
                    float4 cv = f4[(size_t)(i2 * 4 + seg)];
                    float4 dv = f4[(size_t)(i3 * 4 + seg)];
                    ax += (a.x + bv.x) + (cv.x + dv.x);
                    ay += (a.y + bv.y) + (cv.y + dv.y);
                    az += (a.z + bv.z) + (cv.z + dv.z);
                    aw += (a.w + bv.w) + (cv.w + dv.w);
                }
                for (; k < c; ++k) {
                    float4 a = f4[(size_t)(sbuf[s0 + k] * 4 + seg)];
                    ax += a.x; ay += a.y; az += a.z; aw += a.w;
                }
            } else {
                const int* ids = csr + st + s0;
                for (; k + 4 <= c; k += 4) {
                    int i0 = ids[k], i1 = ids[k + 1], i2 = ids[k + 2], i3 = ids[k + 3];
                    float4 a = f4[(size_t)(i0 * 4 + seg)];
                    float4 bv = f4[(size_t)(i1 * 4 + seg)];
                    float4 cv = f4[(size_t)(i2 * 4 + seg)];
                    float4 dv = f4[(size_t)(i3 * 4 + seg)];
                    ax += (a.x + bv.x) + (cv.x + dv.x);
                    ay += (a.y + bv.y) + (cv.y + dv.y);
                    az += (a.z + bv.z) + (cv.z + dv.z);
                    aw += (a.w + bv.w) + (cv.w + dv.w);
                }
                for (; k < c; ++k) {
                    float4 a = f4[(size_t)(ids[k] * 4 + seg)];
                    ax += a.x; ay += a.y; az += a.z; aw += a.w;
                }
            }
            float inv = 1.f / fmaxf((float)c, 1.f);
            size_t o = (size_t)node * 4 + seg;
            float4 z = ((const float4*)z1)[o];
            float4 bb = ((const float4*)b1)[seg];
            float4 r;
            r.x = fmaxf(ax * inv + bb.x + z.x, 0.f);
            r.y = fmaxf(ay * inv + bb.y + z.y, 0.f);
            r.z = fmaxf(az * inv + bb.z + z.z, 0.f);
            r.w = fmaxf(aw * inv + bb.w + z.w, 0.f);
            ((float4*)h)[o] = r;
        }
    }
}

// ---------------------------------------------------------------------------
// K_pair: fused layer-2 on-demand aggregation + pair logits + BCE + final
// mean (ticket). 8 lanes per pair: slot s=sub>>2 (article), seg=sub&3.
// ---------------------------------------------------------------------------
__global__ __launch_bounds__(256) void k_pair(const float* __restrict__ h,
                                              const int* __restrict__ csr,
                                              const int* __restrict__ nodestart,
                                              const int* __restrict__ a1,
                                              const int* __restrict__ a2,
                                              const int* __restrict__ labels,
                                              const float* __restrict__ wsu,
                                              float* __restrict__ out_logits,
                                              float* __restrict__ lacc,
                                              int* __restrict__ ticket,
                                              float* __restrict__ out0,
                                              int B, float invB) {
    __shared__ float lred[32];
    int t = blockIdx.x * 256 + threadIdx.x;
    int p = t >> 3, sub = t & 7;
    int s = sub >> 2, seg = sub & 3;
    int g = threadIdx.x >> 3;
    const float4* h4 = (const float4*)h;
    const float4* wsu4 = (const float4*)wsu;

    float myloss = 0.f;
    if (p < B) {
        int node = s ? a2[p] : a1[p];
        int st = nodestart[node], en = nodestart[node + 1];
        float ax = 0.f, ay = 0.f, az = 0.f, aw = 0.f;
        int k = st;
        for (; k + 2 <= en; k += 2) {
            int s0 = csr[k], s1 = csr[k + 1];
            float4 a = h4[(size_t)(s0 * 4 + seg)];
            float4 b = h4[(size_t)(s1 * 4 + seg)];
            ax += a.x + b.x; ay += a.y + b.y;
            az += a.z + b.z; aw += a.w + b.w;
        }
        if (k < en) {
            float4 a = h4[(size_t)(csr[k] * 4 + seg)];
            ax += a.x; ay += a.y; az += a.z; aw += a.w;
        }
        float inv = 1.f / fmaxf((float)(en - st), 1.f);
        float4 ul = wsu4[s * 4 + seg];
        float4 ur = wsu4[8 + s * 4 + seg];
        float4 hn = h4[(size_t)node * 4 + seg];
        float v = (ax * ul.x + ay * ul.y + az * ul.z + aw * ul.w) * inv
                + (hn.x * ur.x + hn.y * ur.y + hn.z * ur.z + hn.w * ur.w);
#pragma unroll
        for (int off = 4; off; off >>= 1) v += __shfl_xor(v, off, 8);
        if (sub == 0) {
            float l = v + wsu[64] + wsu[65];
            out_logits[p] = l;
            float y = (float)labels[p];
            myloss = fmaxf(l, 0.f) - l * y + log1pf(expf(-fabsf(l)));
        }
    }
    if (sub == 0) lred[g] = myloss;
    __syncthreads();
    if (threadIdx.x == 0) {
        float ssum = 0.f;
#pragma unroll
        for (int k = 0; k < 32; ++k) ssum += lred[k];
        atomicAdd(lacc, ssum);
        __threadfence();
        int tk = atomicAdd(ticket, 1);
        if (tk == (int)gridDim.x - 1) {
            __threadfence();
            float total = atomicAdd(lacc, 0.f);
            out0[0] = total * invB;
        }
    }
}

// ---------------------------------------------------------------------------
extern "C" void kernel_launch(void* const* d_in, const int* in_sizes, int n_in,
                              void* d_out, int out_size, void* d_ws, size_t ws_size,
                              hipStream_t stream) {
    const float* x    = (const float*)d_in[0];
    const float* w1l  = (const float*)d_in[1];
    const float* b1   = (const float*)d_in[2];
    const float* w1r  = (const float*)d_in[3];
    const float* w2l  = (const float*)d_in[4];
    const float* b2v  = (const float*)d_in[5];
    const float* w2r  = (const float*)d_in[6];
    const float* wc   = (const float*)d_in[7];
    const float* bc   = (const float*)d_in[8];
    const int*   ei   = (const int*)d_in[9];
    const int*   a1   = (const int*)d_in[10];
    const int*   a2   = (const int*)d_in[11];
    const int*   lab  = (const int*)d_in[12];

    const int N = in_sizes[0] / DD;
    const int E = in_sizes[9] / 2;
    const int B = in_sizes[10];
    const int NB = (N + BW - 1) / BW;       // 782 for N=100000 (needs N < 2^20)

    const int* src = ei;
    const int* dst = ei + E;

    // workspace layout
    char* ws = (char*)d_ws;
    const size_t NH4 = (size_t)N * HH * 4;
    float* wsu     = (float*)ws;                             // 512 B
    float* y1      = (float*)(ws + 512);                     // [N,16]
    float* z1      = (float*)(ws + 512 + NH4);
    float* h       = (float*)(ws + 512 + 2 * NH4);
    int*   packed  = (int*)  (ws + 512 + 3 * NH4);           // [E]
    int*   csr     = (int*)  (ws + 512 + 3 * NH4 + (size_t)E * 4);  // [E]
    char*  p4      = ws + 512 + 3 * NH4 + 2 * (size_t)E * 4;
    int*   nodest  = (int*)p4;                               // [N+1]
    int*   bstart  = (int*)(p4 + ((size_t)N + 1) * 4);       // [NB+1]
    int*   gcursor = (int*)(p4 + ((size_t)N + 1) * 4 + ((size_t)NB + 1) * 4);  // [NB]
    int*   bcnt    = (int*)(p4 + ((size_t)N + 1) * 4 + (2 * (size_t)NB + 1) * 4); // [NB] zeroed
    float* lacc    = (float*)(p4 + ((size_t)N + 1) * 4 + (3 * (size_t)NB + 1) * 4);// zeroed
    int*   ticket  = (int*)  ((char*)lacc + 4);              // zeroed
    int*   ticket2 = (int*)  ((char*)lacc + 8);              // zeroed

    float* out = (float*)d_out;       // out[0] = loss, out[1..B] = logits

    hipMemsetAsync((void*)bcnt, 0, (size_t)NB * 4 + 12, stream);

    const int E4 = E / 4;
    const int cblocks = (E4 + 1023) / 1024;          // 4096 edges per chunk
    const int xblocks = (N + 63) / 64;

    k_front<<<xblocks + cblocks + 1, 256, 0, stream>>>(
        dst, bcnt, E4, NB, cblocks, xblocks,
        w2l, w2r, b2v, wc, bc, wsu,
        x, w1l, w1r, y1, z1, N,
        bstart, gcursor, nodest, ticket2, E);

    k_bscatter<<<cblocks, 256, 0, stream>>>(src, dst, gcursor, packed, E4, NB);

    k_sortagg<<<NB, 256, 0, stream>>>(packed, bstart, nodest, csr, y1, z1, b1, h, N);

    k_pair<<<(B * 8 + 255) / 256, 256, 0, stream>>>(h, csr, nodest, a1, a2, lab, wsu,
                                                    out + 1, lacc, ticket, out,
                                                    B, 1.0f / (float)B);
}

// Round 9
// 222.261 us; speedup vs baseline: 1.0983x; 1.0983x over previous
//
#include <hip/hip_runtime.h>
#include <hip/hip_bf16.h>

#define DD 128    // feature dim
#define HH 16     // hidden dim
#define BW 128    // bucket width (nodes per bucket) = 1<<7
#define NBMAX 1024
#define SCAP 4096      // LDS slice cap in sortagg (avg slice 2048, max ~2300)

// bf16x2 pack/unpack (RNE)
__device__ __forceinline__ float lo16(unsigned u) { return __uint_as_float(u << 16); }
__device__ __forceinline__ float hi16(unsigned u) { return __uint_as_float(u & 0xffff0000u); }
__device__ __forceinline__ unsigned b16(float f) {
    unsigned u = __float_as_uint(f);
    return (u + 0x7fffu + ((u >> 16) & 1u)) >> 16;
}
__device__ __forceinline__ unsigned pack2(float a, float b) {
    return b16(a) | (b16(b) << 16);
}

// ---------------------------------------------------------------------------
// K1: bucket histogram (4096 edges/block) + classifier-collapse prep (last
// block).
//   wsu[0..15]  = w2_l[j,:].wc[:128]    wsu[16..31] = w2_l[j,:].wc[128:]
//   wsu[32..47] = w2_r[j,:].wc[:128]    wsu[48..63] = w2_r[j,:].wc[128:]
//   wsu[64] = b2.wc[:128] + bc ;  wsu[65] = b2.wc[128:]
// ---------------------------------------------------------------------------
__global__ __launch_bounds__(256) void k_bcount(const int* __restrict__ dst,
                                                int* __restrict__ bcnt,
                                                int E4, int NB, int cblocks,
                                                const float* __restrict__ w2l,
                                                const float* __restrict__ w2r,
                                                const float* __restrict__ b2v,
                                                const float* __restrict__ wc,
                                                const float* __restrict__ bc,
                                                float* __restrict__ wsu) {
    if (blockIdx.x == (unsigned)cblocks) {      // prep block
        int t = threadIdx.x;
        if (t < 64) {
            int k = t >> 4, j = t & 15;
            const float* W = (k < 2) ? w2l : w2r;
            int off = (k & 1) * DD;
            float s = 0.f;
            for (int d = 0; d < DD; ++d) s += W[j * DD + d] * wc[off + d];
            wsu[k * 16 + j] = s;
        } else if (t == 64) {
            float s = bc[0];
            for (int d = 0; d < DD; ++d) s += b2v[d] * wc[d];
            wsu[64] = s;
        } else if (t == 65) {
            float s = 0.f;
            for (int d = 0; d < DD; ++d) s += b2v[d] * wc[DD + d];
            wsu[65] = s;
        }
        return;
    }
    __shared__ int hist[NBMAX];
    for (int i = threadIdx.x; i < NB; i += 256) hist[i] = 0;
    __syncthreads();
    int base = blockIdx.x * 1024;
#pragma unroll
    for (int k = 0; k < 4; ++k) {
        int i4 = base + k * 256 + threadIdx.x;
        if (i4 < E4) {
            int4 d = ((const int4*)dst)[i4];
            atomicAdd(&hist[d.x >> 7], 1);
            atomicAdd(&hist[d.y >> 7], 1);
            atomicAdd(&hist[d.z >> 7], 1);
            atomicAdd(&hist[d.w >> 7], 1);
        }
    }
    __syncthreads();
    for (int i = threadIdx.x; i < NB; i += 256) {
        int h = hist[i];
        if (h) atomicAdd(&bcnt[i], h);
    }
}

// ---------------------------------------------------------------------------
// K2: exclusive scan over NB bucket counts -> bstart (+[NB]=E), gcursor;
// also nodestart[N] = E. Single block of 1024.
// ---------------------------------------------------------------------------
__global__ __launch_bounds__(1024) void k_bscan(const int* __restrict__ bcnt,
                                                int* __restrict__ bstart,
                                                int* __restrict__ gcursor,
                                                int* __restrict__ nodestart,
                                                int NB, int N, int E) {
    __shared__ int sa[1024];
    __shared__ int sb[1024];
    int t = threadIdx.x;
    int v = (t < NB) ? bcnt[t] : 0;
    sa[t] = v;
    __syncthreads();
    int* cur = sa;
    int* nxt = sb;
    for (int off = 1; off < 1024; off <<= 1) {
        int xv = cur[t];
        if (t >= off) xv += cur[t - off];
        nxt[t] = xv;
        __syncthreads();
        int* tmp = cur; cur = nxt; nxt = tmp;
    }
    if (t < NB) {
        int excl = cur[t] - v;
        bstart[t] = excl;
        gcursor[t] = excl;
    }
    if (t == 0) {
        bstart[NB] = cur[1023];
        nodestart[N] = E;
    }
}

// ---------------------------------------------------------------------------
// K3: bucketed scatter (4096 edges/block). LDS hist -> bulk range
// reservation -> packed entries (local<<20 | src) into per-bucket ranges.
// ---------------------------------------------------------------------------
__global__ __launch_bounds__(256) void k_bscatter(const int* __restrict__ src,
                                                  const int* __restrict__ dst,
                                                  int* __restrict__ gcursor,
                                                  int* __restrict__ packed,
                                                  int E4, int NB) {
    __shared__ int hist[NBMAX];
    __shared__ int cur[NBMAX];
    for (int i = threadIdx.x; i < NB; i += 256) hist[i] = 0;
    __syncthreads();
    int base = blockIdx.x * 1024;
    int4 dreg[4];
#pragma unroll
    for (int k = 0; k < 4; ++k) {
        int i4 = base + k * 256 + threadIdx.x;
        if (i4 < E4) {
            int4 d = ((const int4*)dst)[i4];
            dreg[k] = d;
            atomicAdd(&hist[d.x >> 7], 1);
            atomicAdd(&hist[d.y >> 7], 1);
            atomicAdd(&hist[d.z >> 7], 1);
            atomicAdd(&hist[d.w >> 7], 1);
        }
    }
    __syncthreads();
    for (int i = threadIdx.x; i < NB; i += 256) {
        int hv = hist[i];
        cur[i] = hv ? atomicAdd(&gcursor[i], hv) : 0;
    }
    __syncthreads();
#pragma unroll
    for (int k = 0; k < 4; ++k) {
        int i4 = base + k * 256 + threadIdx.x;
        if (i4 < E4) {
            int4 sv = ((const int4*)src)[i4];
            int4 d = dreg[k];
            int p;
            p = atomicAdd(&cur[d.x >> 7], 1); packed[p] = ((d.x & 127) << 20) | sv.x;
            p = atomicAdd(&cur[d.y >> 7], 1); packed[p] = ((d.y & 127) << 20) | sv.y;
            p = atomicAdd(&cur[d.z >> 7], 1); packed[p] = ((d.z & 127) << 20) | sv.z;
            p = atomicAdd(&cur[d.w >> 7], 1); packed[p] = ((d.w & 127) << 20) | sv.w;
        }
    }
}

// ---------------------------------------------------------------------------
// K4: y1 = x @ w1_l (bf16 out), z1 = x @ w1_r (f32 out)
// 64 rows/block; 4 lanes/row; each lane owns 8 outputs.
// ---------------------------------------------------------------------------
__global__ __launch_bounds__(256) void k_xform(const float* __restrict__ x,
                                               const float* __restrict__ w1l,
                                               const float* __restrict__ w1r,
                                               unsigned* __restrict__ y1b,
                                               float* __restrict__ z1, int N) {
    __shared__ float wl[DD * HH];     // 8 KB, layout [d*16 + j]
    __shared__ float wr[DD * HH];     // 8 KB
    __shared__ float xt[64 * 132];    // 33.8 KB

    const int tid  = threadIdx.x;
    const int row0 = blockIdx.x * 64;

    {
        const float4* a = (const float4*)w1l;
        const float4* b = (const float4*)w1r;
        ((float4*)wl)[tid]       = a[tid];
        ((float4*)wl)[tid + 256] = a[tid + 256];
        ((float4*)wr)[tid]       = b[tid];
        ((float4*)wr)[tid + 256] = b[tid + 256];
    }
#pragma unroll
    for (int k = 0; k < 8; ++k) {
        int idx = tid + k * 256;
        int r = idx >> 5, c = idx & 31;
        if (row0 + r < N)
            ((float4*)xt)[r * 33 + c] =
                ((const float4*)(x + (size_t)(row0 + r) * DD))[c];
    }
    __syncthreads();

    const int r = tid >> 2, seg = tid & 3;
    const int row = row0 + r;
    if (row >= N) return;
    float4 accy = {0.f, 0.f, 0.f, 0.f};
    float4 accz = {0.f, 0.f, 0.f, 0.f};
    const float* xrow = &xt[r * 132];
#pragma unroll 8
    for (int d = 0; d < DD; ++d) {
        float xv = xrow[d];
        float4 wl4 = *(const float4*)&wl[d * HH + seg * 4];
        float4 wr4 = *(const float4*)&wr[d * HH + seg * 4];
        accy.x += xv * wl4.x; accy.y += xv * wl4.y;
        accy.z += xv * wl4.z; accy.w += xv * wl4.w;
        accz.x += xv * wr4.x; accz.y += xv * wr4.y;
        accz.z += xv * wr4.z; accz.w += xv * wr4.w;
    }
    uint2 yp; yp.x = pack2(accy.x, accy.y); yp.y = pack2(accy.z, accy.w);
    ((uint2*)y1b)[(size_t)row * 4 + seg] = yp;
    ((float4*)z1)[(size_t)row * 4 + seg] = accz;
}

// ---------------------------------------------------------------------------
// K5: one block per bucket.
//   Phase A: counting-sort the bucket slice in LDS, write nodestart + csr.
//   Phase B: layer-1 mean for the bucket's 128 nodes from the LDS-sorted
//            slice, gathering bf16 y1 (8 B/gather):
//            h = relu(mean(y1[nbrs]) + b1 + z1), h stored bf16.
// Global fallback for oversized buckets.
// ---------------------------------------------------------------------------
__global__ __launch_bounds__(256) void k_sortagg(const int* __restrict__ packed,
                                                 const int* __restrict__ bstart,
                                                 int* __restrict__ nodestart,
                                                 int* __restrict__ csr,
                                                 const unsigned* __restrict__ y1b,
                                                 const float* __restrict__ z1,
                                                 const float* __restrict__ b1,
                                                 unsigned* __restrict__ hb, int N) {
    __shared__ int buf[SCAP];
    __shared__ int sbuf[SCAP];
    __shared__ int hist[BW];
    __shared__ int exs[BW];
    __shared__ int curs[BW];
    __shared__ int wtot;
    const int tid = threadIdx.x;
    const int b = blockIdx.x;
    const int st = bstart[b], en = bstart[b + 1], cnt = en - st;
    const bool inlds = (cnt <= SCAP);

    if (tid < BW) hist[tid] = 0;
    __syncthreads();
    if (inlds) {
        for (int i = tid; i < cnt; i += 256) {
            int e = packed[st + i];
            buf[i] = e;
            atomicAdd(&hist[e >> 20], 1);
        }
    } else {
        for (int i = tid; i < cnt; i += 256)
            atomicAdd(&hist[packed[st + i] >> 20], 1);
    }
    __syncthreads();

    int v = 0, s = 0;
    if (tid < BW) {
        int lane = tid & 63;
        v = hist[tid];
        s = v;
#pragma unroll
        for (int off = 1; off < 64; off <<= 1) {
            int u = __shfl_up(s, off, 64);
            if (lane >= off) s += u;
        }
        if (tid == 63) wtot = s;
    }
    __syncthreads();
    if (tid < BW) {
        int ex = s - v + ((tid >= 64) ? wtot : 0);
        exs[tid] = ex;
        curs[tid] = ex;
        int node = (b << 7) + tid;
        if (node < N) nodestart[node] = st + ex;
    }
    __syncthreads();

    if (inlds) {
        for (int i = tid; i < cnt; i += 256) {
            int e = buf[i];
            int p = atomicAdd(&curs[e >> 20], 1);
            sbuf[p] = e & 0xFFFFF;
        }
        __syncthreads();
        for (int i = tid; i < cnt; i += 256) csr[st + i] = sbuf[i];  // coalesced
    } else {
        for (int i = tid; i < cnt; i += 256) {
            int e = packed[st + i];
            int p = atomicAdd(&curs[e >> 20], 1);
            csr[st + p] = e & 0xFFFFF;
        }
        __threadfence_block();
        __syncthreads();
    }

    // ---- Phase B: aggregate 128 nodes (4 lanes/node, 2 halves) ----
    const uint2* f2 = (const uint2*)y1b;
#pragma unroll
    for (int half = 0; half < 2; ++half) {
        int l = (tid >> 2) + half * 64;
        int seg = tid & 3;
        int node = (b << 7) + l;
        if (node < N) {
            int s0 = exs[l], c = hist[l];
            float ax = 0.f, ay = 0.f, az = 0.f, aw = 0.f;
            int k = 0;
            if (inlds) {
                for (; k + 4 <= c; k += 4) {
                    uint2 a = f2[(size_t)(sbuf[s0 + k]     * 4 + seg)];
                    uint2 bv = f2[(size_t)(sbuf[s0 + k + 1] * 4 + seg)];
                    uint2 cv = f2[(size_t)(sbuf[s0 + k + 2] * 4 + seg)];
                    uint2 dv = f2[(size_t)(sbuf[s0 + k + 3] * 4 + seg)];
                    ax += (lo16(a.x) + lo16(bv.x)) + (lo16(cv.x) + lo16(dv.x));
                    ay += (hi16(a.x) + hi16(bv.x)) + (hi16(cv.x) + hi16(dv.x));
                    az += (lo16(a.y) + lo16(bv.y)) + (lo16(cv.y) + lo16(dv.y));
                    aw += (hi16(a.y) + hi16(bv.y)) + (hi16(cv.y) + hi16(dv.y));
                }
                for (; k < c; ++k) {
                    uint2 a = f2[(size_t)(sbuf[s0 + k] * 4 + seg)];
                    ax += lo16(a.x); ay += hi16(a.x);
                    az += lo16(a.y); aw += hi16(a.y);
                }
            } else {
                const int* ids = csr + st + s0;
                for (; k + 4 <= c; k += 4) {
                    uint2 a = f2[(size_t)(ids[k]     * 4 + seg)];
                    uint2 bv = f2[(size_t)(ids[k + 1] * 4 + seg)];
                    uint2 cv = f2[(size_t)(ids[k + 2] * 4 + seg)];
                    uint2 dv = f2[(size_t)(ids[k + 3] * 4 + seg)];
                    ax += (lo16(a.x) + lo16(bv.x)) + (lo16(cv.x) + lo16(dv.x));
                    ay += (hi16(a.x) + hi16(bv.x)) + (hi16(cv.x) + hi16(dv.x));
                    az += (lo16(a.y) + lo16(bv.y)) + (lo16(cv.y) + lo16(dv.y));
                    aw += (hi16(a.y) + hi16(bv.y)) + (hi16(cv.y) + hi16(dv.y));
                }
                for (; k < c; ++k) {
                    uint2 a = f2[(size_t)(ids[k] * 4 + seg)];
                    ax += lo16(a.x); ay += hi16(a.x);
                    az += lo16(a.y); aw += hi16(a.y);
                }
            }
            float inv = 1.f / fmaxf((float)c, 1.f);
            size_t o = (size_t)node * 4 + seg;
            float4 z = ((const float4*)z1)[o];
            float4 bb = ((const float4*)b1)[seg];
            float hx = fmaxf(ax * inv + bb.x + z.x, 0.f);
            float hy = fmaxf(ay * inv + bb.y + z.y, 0.f);
            float hz = fmaxf(az * inv + bb.z + z.z, 0.f);
            float hw = fmaxf(aw * inv + bb.w + z.w, 0.f);
            uint2 hp; hp.x = pack2(hx, hy); hp.y = pack2(hz, hw);
            ((uint2*)hb)[o] = hp;
        }
    }
}

// ---------------------------------------------------------------------------
// K6: fused layer-2 on-demand aggregation + pair logits + BCE + final mean
// (ticket). 8 lanes per pair: slot s=sub>>2 (article), seg=sub&3. Gathers
// bf16 h (8 B per edge per lane).
// ---------------------------------------------------------------------------
__global__ __launch_bounds__(256) void k_pair(const unsigned* __restrict__ hb,
                                              const int* __restrict__ csr,
                                              const int* __restrict__ nodestart,
                                              const int* __restrict__ a1,
                                              const int* __restrict__ a2,
                                              const int* __restrict__ labels,
                                              const float* __restrict__ wsu,
                                              float* __restrict__ out_logits,
                                              float* __restrict__ lacc,
                                              int* __restrict__ ticket,
                                              float* __restrict__ out0,
                                              int B, float invB) {
    __shared__ float lred[32];
    int t = blockIdx.x * 256 + threadIdx.x;
    int p = t >> 3, sub = t & 7;
    int s = sub >> 2, seg = sub & 3;
    int g = threadIdx.x >> 3;
    const uint2* h2 = (const uint2*)hb;
    const float4* wsu4 = (const float4*)wsu;

    float myloss = 0.f;
    if (p < B) {
        int node = s ? a2[p] : a1[p];
        int st = nodestart[node], en = nodestart[node + 1];
        float ax = 0.f, ay = 0.f, az = 0.f, aw = 0.f;
        int k = st;
        for (; k + 2 <= en; k += 2) {
            uint2 a = h2[(size_t)(csr[k]     * 4 + seg)];
            uint2 b = h2[(size_t)(csr[k + 1] * 4 + seg)];
            ax += lo16(a.x) + lo16(b.x); ay += hi16(a.x) + hi16(b.x);
            az += lo16(a.y) + lo16(b.y); aw += hi16(a.y) + hi16(b.y);
        }
        if (k < en) {
            uint2 a = h2[(size_t)(csr[k] * 4 + seg)];
            ax += lo16(a.x); ay += hi16(a.x);
            az += lo16(a.y); aw += hi16(a.y);
        }
        float inv = 1.f / fmaxf((float)(en - st), 1.f);
        float4 ul = wsu4[s * 4 + seg];
        float4 ur = wsu4[8 + s * 4 + seg];
        uint2 hn = h2[(size_t)node * 4 + seg];
        float v = (ax * ul.x + ay * ul.y + az * ul.z + aw * ul.w) * inv
                + (lo16(hn.x) * ur.x + hi16(hn.x) * ur.y
                 + lo16(hn.y) * ur.z + hi16(hn.y) * ur.w);
#pragma unroll
        for (int off = 4; off; off >>= 1) v += __shfl_xor(v, off, 8);
        if (sub == 0) {
            float l = v + wsu[64] + wsu[65];
            out_logits[p] = l;
            float y = (float)labels[p];
            myloss = fmaxf(l, 0.f) - l * y + log1pf(expf(-fabsf(l)));
        }
    }
    if (sub == 0) lred[g] = myloss;
    __syncthreads();
    if (threadIdx.x == 0) {
        float ssum = 0.f;
#pragma unroll
        for (int k = 0; k < 32; ++k) ssum += lred[k];
        atomicAdd(lacc, ssum);
        __threadfence();
        int tk = atomicAdd(ticket, 1);
        if (tk == (int)gridDim.x - 1) {
            __threadfence();
            float total = atomicAdd(lacc, 0.f);
            out0[0] = total * invB;
        }
    }
}

// ---------------------------------------------------------------------------
extern "C" void kernel_launch(void* const* d_in, const int* in_sizes, int n_in,
                              void* d_out, int out_size, void* d_ws, size_t ws_size,
                              hipStream_t stream) {
    const float* x    = (const float*)d_in[0];
    const float* w1l  = (const float*)d_in[1];
    const float* b1   = (const float*)d_in[2];
    const float* w1r  = (const float*)d_in[3];
    const float* w2l  = (const float*)d_in[4];
    const float* b2v  = (const float*)d_in[5];
    const float* w2r  = (const float*)d_in[6];
    const float* wc   = (const float*)d_in[7];
    const float* bc   = (const float*)d_in[8];
    const int*   ei   = (const int*)d_in[9];
    const int*   a1   = (const int*)d_in[10];
    const int*   a2   = (const int*)d_in[11];
    const int*   lab  = (const int*)d_in[12];

    const int N = in_sizes[0] / DD;
    const int E = in_sizes[9] / 2;
    const int B = in_sizes[10];
    const int NB = (N + BW - 1) / BW;       // 782 for N=100000 (needs N < 2^20)

    const int* src = ei;
    const int* dst = ei + E;

    // workspace layout
    char* ws = (char*)d_ws;
    float*    wsu    = (float*)ws;                            // 512 B
    unsigned* y1b    = (unsigned*)(ws + 512);                 // [N,16] bf16 (32 B/row)
    unsigned* hb     = (unsigned*)(ws + 512 + (size_t)N * 32);
    float*    z1     = (float*)   (ws + 512 + (size_t)N * 64);
    int*      packed = (int*)     (ws + 512 + (size_t)N * 128);
    int*      csr    = (int*)     (ws + 512 + (size_t)N * 128 + (size_t)E * 4);
    char*     p4     = ws + 512 + (size_t)N * 128 + 2 * (size_t)E * 4;
    int*   nodest  = (int*)p4;                               // [N+1]
    int*   bstart  = (int*)(p4 + ((size_t)N + 1) * 4);       // [NB+1]
    int*   gcursor = (int*)(p4 + ((size_t)N + 1) * 4 + ((size_t)NB + 1) * 4);  // [NB]
    int*   bcnt    = (int*)(p4 + ((size_t)N + 1) * 4 + (2 * (size_t)NB + 1) * 4); // [NB] zeroed
    float* lacc    = (float*)(p4 + ((size_t)N + 1) * 4 + (3 * (size_t)NB + 1) * 4);// zeroed
    int*   ticket  = (int*)((char*)lacc + 4);                // zeroed

    float* out = (float*)d_out;       // out[0] = loss, out[1..B] = logits

    hipMemsetAsync((void*)bcnt, 0, (size_t)NB * 4 + 8, stream);

    const int E4 = E / 4;
    const int cblocks = (E4 + 1023) / 1024;          // 4096 edges per chunk

    k_bcount<<<cblocks + 1, 256, 0, stream>>>(dst, bcnt, E4, NB, cblocks,
                                              w2l, w2r, b2v, wc, bc, wsu);
    k_bscan<<<1, 1024, 0, stream>>>(bcnt, bstart, gcursor, nodest, NB, N, E);
    k_bscatter<<<cblocks, 256, 0, stream>>>(src, dst, gcursor, packed, E4, NB);

    k_xform<<<(N + 63) / 64, 256, 0, stream>>>(x, w1l, w1r, y1b, z1, N);

    k_sortagg<<<NB, 256, 0, stream>>>(packed, bstart, nodest, csr, y1b, z1, b1, hb, N);

    k_pair<<<(B * 8 + 255) / 256, 256, 0, stream>>>(hb, csr, nodest, a1, a2, lab, wsu,
                                                    out + 1, lacc, ticket, out,
                                                    B, 1.0f / (float)B);
}